// Round 2
// baseline (235.425 us; speedup 1.0000x reference)
//
#include <hip/hip_runtime.h>
#include <hip/hip_bf16.h>

// Two pairwise MLPs (ChG, DG) over 1024x1024 pairs, then A_chg @ A_gd, sigmoid.
// Outputs concat: [0:1M) sigmoid(A_chd), [1M:2M) A_chg, [2M:3M) A_gd (fp32).
//
// Numerics strategy (R2): split-bf16 (hi+lo) everywhere MFMA touches data, so
// effective precision ~2^-17 instead of bf16's 2^-8. The R1 failure (0.1875 on
// output 0) was bf16 rounding noise amplified ~18x by the K=1024 final GEMM.
//
//   P1 precompute_hlr : HL/HR fp32 (first Dense split), b0 folded into HL.
//   P2 pack_w1        : W1 -> bf16 hi+lo MFMA B-fragments, both branches.
//   branch_kernel     : h=relu(hl+hr) fp32 -> split hi/lo A-frags; 3-term MFMA
//                       vs W1 hi/lo; VALU epilogue relu(+b1), Dense(1) dot via
//                       16-lane shfl_xor butterfly, elu; store fp32 A to d_out
//                       and bf16 hi/lo copies to ws (A_gd transposed).
//   gemm_sig          : 64x64-tile 3-term bf16 MFMA GEMM K=1024 + sigmoid.

typedef __attribute__((ext_vector_type(8))) short short8;
typedef __attribute__((ext_vector_type(4))) float floatx4;

__device__ inline unsigned short f2bf(float x) {
    unsigned int u = __float_as_uint(x);
    u += 0x7fffu + ((u >> 16) & 1u);
    return (unsigned short)(u >> 16);
}

__device__ inline void split_bf(float x, unsigned short& hi, unsigned short& lo) {
    unsigned short h = f2bf(x);
    float hf = __uint_as_float(((unsigned int)h) << 16);
    hi = h;
    lo = f2bf(x - hf);   // exact residual in fp32, rounded to bf16
}

// ---------------------------------------------------------------- P1
// wsf (floats): seg0 HL_chg(+b0c), seg1 HR_chg, seg2 HL_dg(+b0d), seg3 HR_dg
// each [1024][128]
__global__ __launch_bounds__(256) void precompute_hlr(
    const float* __restrict__ Xch, const float* __restrict__ Xg,
    const float* __restrict__ Xd,
    const float* __restrict__ Wc0, const float* __restrict__ bc0,
    const float* __restrict__ Wd0, const float* __restrict__ bd0,
    float* __restrict__ wsf)
{
    int t = blockIdx.x * 256 + threadIdx.x;   // 524288 threads
    int seg = t >> 17;
    int i = (t >> 7) & 1023;
    int k = t & 127;
    const float* X;
    const float* W;
    float s = 0.f;
    int wo = 0;
    if (seg == 0)      { X = Xch; W = Wc0; s = bc0[k]; }
    else if (seg == 1) { X = Xg;  W = Wc0; wo = 5; }
    else if (seg == 2) { X = Xg;  W = Wd0; s = bd0[k]; }
    else               { X = Xd;  W = Wd0; wo = 5; }
#pragma unroll
    for (int j = 0; j < 5; ++j)
        s += X[i * 5 + j] * W[(wo + j) * 128 + k];
    wsf[t] = s;
}

// ---------------------------------------------------------------- P2
// w1frag layout: [br][part(hi/lo)][frag=ks*4+nt][lane][j]  (2*2*16*64*8 shorts)
// frag element = W1[ks*32 + (lane>>4)*8 + j][nt*16 + (lane&15)]
__global__ __launch_bounds__(256) void pack_w1(
    const float* __restrict__ W1c, const float* __restrict__ W1d,
    unsigned short* __restrict__ w1frag)
{
    int t = blockIdx.x * 256 + threadIdx.x;   // 32768 threads
    int br   = t >> 14;
    int part = (t >> 13) & 1;
    int frag = (t >> 9) & 15;
    int lane = (t >> 3) & 63;
    int j    = t & 7;
    int ks = frag >> 2, nt = frag & 3;
    int row = ks * 32 + (lane >> 4) * 8 + j;
    int col = nt * 16 + (lane & 15);
    const float* W = br ? W1d : W1c;
    unsigned short hi, lo;
    split_bf(W[row * 64 + col], hi, lo);
    w1frag[t] = part ? lo : hi;
}

// ---------------------------------------------------------------- branch
#define LCHUNK 64

__global__ __launch_bounds__(256) void branch_kernel(
    const float* __restrict__ wsf,
    const float* __restrict__ b1_chg, const float* __restrict__ wr_chg, const float* __restrict__ br_chg,
    const float* __restrict__ b1_dg,  const float* __restrict__ wr_dg,  const float* __restrict__ br_dg,
    const unsigned short* __restrict__ w1frag,
    float* __restrict__ d_out,
    unsigned short* __restrict__ wsb)
{
    __shared__ float hl_tile[LCHUNK * 128];   // 32 KB

    const int br = blockIdx.z;
    const float* HL = wsf + (br ? 262144 : 0);
    const float* HR = wsf + (br ? 393216 : 131072);
    const float* b1 = br ? b1_dg : b1_chg;
    const float* wr = br ? wr_dg : wr_chg;
    const float brv = br ? br_dg[0] : br_chg[0];
    float* outA = d_out + (br ? 2097152 : 1048576);
    // wsb: [0:1M) Achg_hi [ch][g], [1M:2M) Achg_lo, [2M:3M) AgdT_hi [d][g], [3M:4M) AgdT_lo
    unsigned short* outBh = wsb + (br ? 2097152 : 0);
    unsigned short* outBl = wsb + (br ? 3145728 : 1048576);

    const int tid = threadIdx.x;
    const int lbase = blockIdx.y * LCHUNK;
    const int rbase = blockIdx.x * 64;

    {   // stage HL tile (fp32, b0 folded)
        const float4* src = (const float4*)(HL + lbase * 128);
        float4* dst = (float4*)hl_tile;
#pragma unroll
        for (int i = 0; i < (LCHUNK * 128 / 4) / 256; ++i)
            dst[tid + i * 256] = src[tid + i * 256];
    }

    const int lane = tid & 63, wave = tid >> 6;
    const int m = lane & 15, quad = lane >> 4;
    const int rm = rbase + wave * 16 + m;

    // HR in A-fragment k-order: k = ks*32 + quad*8 + j
    float hr[4][8];
#pragma unroll
    for (int ks = 0; ks < 4; ++ks) {
        const float4* p = (const float4*)(HR + rm * 128 + ks * 32 + quad * 8);
        float4 v0 = p[0], v1 = p[1];
        hr[ks][0] = v0.x; hr[ks][1] = v0.y; hr[ks][2] = v0.z; hr[ks][3] = v0.w;
        hr[ks][4] = v1.x; hr[ks][5] = v1.y; hr[ks][6] = v1.z; hr[ks][7] = v1.w;
    }

    // W1 hi/lo B-fragments
    short8 w1h[4][4], w1l[4][4];
    {
        const short8* wfh = (const short8*)(w1frag + br * 16384);
        const short8* wfl = (const short8*)(w1frag + br * 16384 + 8192);
#pragma unroll
        for (int f = 0; f < 16; ++f) {
            w1h[f >> 2][f & 3] = wfh[f * 64 + lane];
            w1l[f >> 2][f & 3] = wfl[f * 64 + lane];
        }
    }

    float b1v[4], wrv[4];
#pragma unroll
    for (int nt = 0; nt < 4; ++nt) {
        b1v[nt] = b1[nt * 16 + m];
        wrv[nt] = wr[nt * 16 + m];
    }

    __syncthreads();

    for (int l = 0; l < LCHUNK; ++l) {
        // h = relu(hl+hr) fp32 -> split-bf16 A-fragments
        short8 ah[4], al[4];
#pragma unroll
        for (int ks = 0; ks < 4; ++ks) {
            const float4* hp = (const float4*)(hl_tile + l * 128 + ks * 32 + quad * 8);
            float4 h0 = hp[0], h1 = hp[1];
            float hv[8];
            hv[0] = h0.x + hr[ks][0]; hv[1] = h0.y + hr[ks][1];
            hv[2] = h0.z + hr[ks][2]; hv[3] = h0.w + hr[ks][3];
            hv[4] = h1.x + hr[ks][4]; hv[5] = h1.y + hr[ks][5];
            hv[6] = h1.z + hr[ks][6]; hv[7] = h1.w + hr[ks][7];
            short8 th, tl;
#pragma unroll
            for (int j = 0; j < 8; ++j) {
                unsigned short hi, lo;
                split_bf(fmaxf(hv[j], 0.f), hi, lo);
                th[j] = (short)hi; tl[j] = (short)lo;
            }
            ah[ks] = th; al[ks] = tl;
        }

        floatx4 acc[4];
#pragma unroll
        for (int nt = 0; nt < 4; ++nt)
            acc[nt] = (floatx4){0.f, 0.f, 0.f, 0.f};
#pragma unroll
        for (int ks = 0; ks < 4; ++ks)
#pragma unroll
            for (int nt = 0; nt < 4; ++nt) {
                acc[nt] = __builtin_amdgcn_mfma_f32_16x16x32_bf16(ah[ks], w1h[ks][nt], acc[nt], 0, 0, 0);
                acc[nt] = __builtin_amdgcn_mfma_f32_16x16x32_bf16(al[ks], w1h[ks][nt], acc[nt], 0, 0, 0);
                acc[nt] = __builtin_amdgcn_mfma_f32_16x16x32_bf16(ah[ks], w1l[ks][nt], acc[nt], 0, 0, 0);
            }

        // h1 = relu(acc + b1); partial Dense(1) dot (lane covers n = nt*16+m)
        float p[4] = {0.f, 0.f, 0.f, 0.f};
#pragma unroll
        for (int nt = 0; nt < 4; ++nt)
#pragma unroll
            for (int r = 0; r < 4; ++r)
                p[r] += fmaxf(acc[nt][r] + b1v[nt], 0.f) * wrv[nt];

#pragma unroll
        for (int mask = 1; mask < 16; mask <<= 1)
#pragma unroll
            for (int r = 0; r < 4; ++r)
                p[r] += __shfl_xor(p[r], mask, 64);

        if (m < 4) {
            float v = p[m] + brv;                        // pair row = quad*4 + m
            float A = v > 0.f ? v : (expf(v) - 1.f);     // elu
            int r_out = rbase + wave * 16 + quad * 4 + m;
            int l_out = lbase + l;
            outA[l_out * 1024 + r_out] = A;
            unsigned short hi, lo;
            split_bf(A, hi, lo);
            if (br == 0) {
                outBh[l_out * 1024 + r_out] = hi;        // Achg [ch][g]
                outBl[l_out * 1024 + r_out] = lo;
            } else {
                outBh[r_out * 1024 + l_out] = hi;        // AgdT [d][g]
                outBl[r_out * 1024 + l_out] = lo;
            }
        }
    }
}

// ---------------------------------------------------------------- final GEMM + sigmoid
// C[ch][d] = sum_g Achg[ch][g]*Agd[g][d]; 3-term split-bf16 MFMA.
__global__ __launch_bounds__(256) void gemm_sig(
    const unsigned short* __restrict__ Ah, const unsigned short* __restrict__ Al,
    const unsigned short* __restrict__ BTh, const unsigned short* __restrict__ BTl,
    float* __restrict__ out0)
{
    __shared__ unsigned short Ath[64 * 72];   // +8 pad
    __shared__ unsigned short Atl[64 * 72];
    __shared__ unsigned short Bth[64 * 72];
    __shared__ unsigned short Btl[64 * 72];

    const int tid = threadIdx.x, lane = tid & 63, wave = tid >> 6;
    const int m = lane & 15, quad = lane >> 4;
    const int chbase = blockIdx.y * 64, dbase = blockIdx.x * 64;
    const int wrow = (wave >> 1) * 32, wcol = (wave & 1) * 32;

    floatx4 acc[2][2];
#pragma unroll
    for (int mi = 0; mi < 2; ++mi)
#pragma unroll
        for (int ni = 0; ni < 2; ++ni)
            acc[mi][ni] = (floatx4){0.f, 0.f, 0.f, 0.f};

    for (int kb = 0; kb < 1024; kb += 64) {
        __syncthreads();
#pragma unroll
        for (int i = 0; i < 2; ++i) {
            int idx = tid + i * 256;
            int row = idx >> 3, c4 = idx & 7;
            *(uint4*)(Ath + row * 72 + c4 * 8) =
                *(const uint4*)(Ah + (chbase + row) * 1024 + kb + c4 * 8);
            *(uint4*)(Atl + row * 72 + c4 * 8) =
                *(const uint4*)(Al + (chbase + row) * 1024 + kb + c4 * 8);
            *(uint4*)(Bth + row * 72 + c4 * 8) =
                *(const uint4*)(BTh + (dbase + row) * 1024 + kb + c4 * 8);
            *(uint4*)(Btl + row * 72 + c4 * 8) =
                *(const uint4*)(BTl + (dbase + row) * 1024 + kb + c4 * 8);
        }
        __syncthreads();
#pragma unroll
        for (int k2 = 0; k2 < 2; ++k2) {
            int koff = k2 * 32 + quad * 8;
            short8 ah[2], al[2], bh[2], bl[2];
            ah[0] = *(const short8*)(Ath + (wrow + m) * 72 + koff);
            ah[1] = *(const short8*)(Ath + (wrow + 16 + m) * 72 + koff);
            al[0] = *(const short8*)(Atl + (wrow + m) * 72 + koff);
            al[1] = *(const short8*)(Atl + (wrow + 16 + m) * 72 + koff);
            bh[0] = *(const short8*)(Bth + (wcol + m) * 72 + koff);
            bh[1] = *(const short8*)(Bth + (wcol + 16 + m) * 72 + koff);
            bl[0] = *(const short8*)(Btl + (wcol + m) * 72 + koff);
            bl[1] = *(const short8*)(Btl + (wcol + 16 + m) * 72 + koff);
#pragma unroll
            for (int mi = 0; mi < 2; ++mi)
#pragma unroll
                for (int ni = 0; ni < 2; ++ni) {
                    acc[mi][ni] = __builtin_amdgcn_mfma_f32_16x16x32_bf16(ah[mi], bh[ni], acc[mi][ni], 0, 0, 0);
                    acc[mi][ni] = __builtin_amdgcn_mfma_f32_16x16x32_bf16(al[mi], bh[ni], acc[mi][ni], 0, 0, 0);
                    acc[mi][ni] = __builtin_amdgcn_mfma_f32_16x16x32_bf16(ah[mi], bl[ni], acc[mi][ni], 0, 0, 0);
                }
        }
    }

#pragma unroll
    for (int mi = 0; mi < 2; ++mi)
#pragma unroll
        for (int ni = 0; ni < 2; ++ni)
#pragma unroll
            for (int r = 0; r < 4; ++r) {
                int row = chbase + wrow + mi * 16 + quad * 4 + r;
                int col = dbase + wcol + ni * 16 + m;
                float v = acc[mi][ni][r];
                out0[row * 1024 + col] = 1.f / (1.f + expf(-v));
            }
}

// ---------------------------------------------------------------- launch
extern "C" void kernel_launch(void* const* d_in, const int* in_sizes, int n_in,
                              void* d_out, int out_size, void* d_ws, size_t ws_size,
                              hipStream_t stream) {
    const float* Xch = (const float*)d_in[0];
    const float* Xg  = (const float*)d_in[1];
    const float* Xd  = (const float*)d_in[2];
    const float* Wc0 = (const float*)d_in[3];
    const float* bc0 = (const float*)d_in[4];
    const float* Wc1 = (const float*)d_in[5];
    const float* bc1 = (const float*)d_in[6];
    const float* Wcr = (const float*)d_in[7];
    const float* bcr = (const float*)d_in[8];
    const float* Wd0 = (const float*)d_in[9];
    const float* bd0 = (const float*)d_in[10];
    const float* Wd1 = (const float*)d_in[11];
    const float* bd1 = (const float*)d_in[12];
    const float* Wdr = (const float*)d_in[13];
    const float* bdr = (const float*)d_in[14];

    float* out = (float*)d_out;
    float* wsf = (float*)d_ws;                               // 4x1024x128 fp32 = 2 MB
    unsigned short* wsb = (unsigned short*)(wsf + 524288);   // 4x 1M bf16 = 8 MB
    unsigned short* w1frag = wsb + 4194304;                  // 32768 bf16

    precompute_hlr<<<2048, 256, 0, stream>>>(Xch, Xg, Xd, Wc0, bc0, Wd0, bd0, wsf);
    pack_w1<<<128, 256, 0, stream>>>(Wc1, Wd1, w1frag);

    dim3 gb(16, 16, 2);
    branch_kernel<<<gb, 256, 0, stream>>>(wsf, bc1, Wcr, bcr, bd1, Wdr, bdr,
                                          w1frag, out, wsb);

    dim3 gg(16, 16);
    gemm_sig<<<gg, 256, 0, stream>>>(wsb, wsb + 1048576,
                                     wsb + 2097152, wsb + 3145728, out);
}

// Round 4
// 176.509 us; speedup vs baseline: 1.3338x; 1.3338x over previous
//
#include <hip/hip_runtime.h>
#include <hip/hip_bf16.h>

// Two pairwise MLPs (ChG, DG) over 1024x1024 pairs, then A_chg @ A_gd, sigmoid.
// Outputs concat: [0:1M) sigmoid(A_chd), [1M:2M) A_chg, [2M:3M) A_gd (fp32).
//
// R4: fp16 single-term MFMA everywhere (was split-bf16 3-term). fp16's 2^-11
// rel error keeps final sigmoid error ~0.02 (<0.0484 threshold) while cutting
// branch MFMA 3x and the per-pair h packing from ~11 VALU ops/elem to ~2.5
// (v_cvt_pkrtz_f16_f32 packs 2 elems/op). LCHUNK 32 -> 1024 blocks = 4/CU.
// (R3 was a compile fix: cvt_pkrtz returns __fp16x2, not _Float16x2.)

typedef _Float16 half8 __attribute__((ext_vector_type(8)));
typedef __fp16 fp16x2 __attribute__((ext_vector_type(2)));
typedef float floatx4 __attribute__((ext_vector_type(4)));

// ---------------------------------------------------------------- P1
// wsf (floats): seg0 HL_chg(+b0c), seg1 HR_chg, seg2 HL_dg(+b0d), seg3 HR_dg
// each [1024][128]
__global__ __launch_bounds__(256) void precompute_hlr(
    const float* __restrict__ Xch, const float* __restrict__ Xg,
    const float* __restrict__ Xd,
    const float* __restrict__ Wc0, const float* __restrict__ bc0,
    const float* __restrict__ Wd0, const float* __restrict__ bd0,
    float* __restrict__ wsf)
{
    int t = blockIdx.x * 256 + threadIdx.x;   // 524288 threads
    int seg = t >> 17;
    int i = (t >> 7) & 1023;
    int k = t & 127;
    const float* X;
    const float* W;
    float s = 0.f;
    int wo = 0;
    if (seg == 0)      { X = Xch; W = Wc0; s = bc0[k]; }
    else if (seg == 1) { X = Xg;  W = Wc0; wo = 5; }
    else if (seg == 2) { X = Xg;  W = Wd0; s = bd0[k]; }
    else               { X = Xd;  W = Wd0; wo = 5; }
#pragma unroll
    for (int j = 0; j < 5; ++j)
        s += X[i * 5 + j] * W[(wo + j) * 128 + k];
    wsf[t] = s;
}

// ---------------------------------------------------------------- P2
// w1frag[br][frag=ks*4+nt][lane][j] = f16( W1[ks*32+(lane>>4)*8+j][nt*16+(lane&15)] )
__global__ __launch_bounds__(256) void pack_w1(
    const float* __restrict__ W1c, const float* __restrict__ W1d,
    _Float16* __restrict__ w1frag)
{
    int t = blockIdx.x * 256 + threadIdx.x;   // 16384 threads
    int br   = t >> 13;
    int frag = (t >> 9) & 15;
    int lane = (t >> 3) & 63;
    int j    = t & 7;
    int ks = frag >> 2, nt = frag & 3;
    int row = ks * 32 + (lane >> 4) * 8 + j;
    int col = nt * 16 + (lane & 15);
    const float* W = br ? W1d : W1c;
    w1frag[t] = (_Float16)W[row * 64 + col];   // RNE
}

// ---------------------------------------------------------------- branch
#define LCHUNK 32

__global__ __launch_bounds__(256) void branch_kernel(
    const float* __restrict__ wsf,
    const float* __restrict__ b1_chg, const float* __restrict__ wr_chg, const float* __restrict__ br_chg,
    const float* __restrict__ b1_dg,  const float* __restrict__ wr_dg,  const float* __restrict__ br_dg,
    const _Float16* __restrict__ w1frag,
    float* __restrict__ d_out,
    _Float16* __restrict__ wsh)   // [0:1M) Achg f16 [ch][g], [1M:2M) AgdT f16 [d][g]
{
    __shared__ float hl_tile[LCHUNK * 128];   // 16 KB

    const int br = blockIdx.z;
    const float* HL = wsf + (br ? 262144 : 0);
    const float* HR = wsf + (br ? 393216 : 131072);
    const float* b1 = br ? b1_dg : b1_chg;
    const float* wr = br ? wr_dg : wr_chg;
    const float brv = br ? br_dg[0] : br_chg[0];
    float* outA = d_out + (br ? 2097152 : 1048576);
    _Float16* outB = wsh + (br ? 1048576 : 0);

    const int tid = threadIdx.x;
    const int lbase = blockIdx.y * LCHUNK;
    const int rbase = blockIdx.x * 64;

    {   // stage HL tile (fp32, b0 folded): 32*128 floats = 1024 float4
        const float4* src = (const float4*)(HL + lbase * 128);
        float4* dst = (float4*)hl_tile;
#pragma unroll
        for (int i = 0; i < (LCHUNK * 128 / 4) / 256; ++i)
            dst[tid + i * 256] = src[tid + i * 256];
    }

    const int lane = tid & 63, wave = tid >> 6;
    const int m = lane & 15, quad = lane >> 4;
    const int rm = rbase + wave * 16 + m;

    // HR in A-fragment k-order: k = ks*32 + quad*8 + j
    float hr[4][8];
#pragma unroll
    for (int ks = 0; ks < 4; ++ks) {
        const float4* p = (const float4*)(HR + rm * 128 + ks * 32 + quad * 8);
        float4 v0 = p[0], v1 = p[1];
        hr[ks][0] = v0.x; hr[ks][1] = v0.y; hr[ks][2] = v0.z; hr[ks][3] = v0.w;
        hr[ks][4] = v1.x; hr[ks][5] = v1.y; hr[ks][6] = v1.z; hr[ks][7] = v1.w;
    }

    // W1 B-fragments (f16)
    half8 w1f[4][4];
    {
        const half8* wf = (const half8*)(w1frag + br * 8192);
#pragma unroll
        for (int f = 0; f < 16; ++f)
            w1f[f >> 2][f & 3] = wf[f * 64 + lane];
    }

    float b1v[4], wrv[4];
#pragma unroll
    for (int nt = 0; nt < 4; ++nt) {
        b1v[nt] = b1[nt * 16 + m];
        wrv[nt] = wr[nt * 16 + m];
    }

    __syncthreads();

    for (int l = 0; l < LCHUNK; ++l) {
        // h = relu(hl + hr) -> fp16 A-fragments (pkrtz: 2 elems/op)
        half8 a[4];
#pragma unroll
        for (int ks = 0; ks < 4; ++ks) {
            const float4* hp = (const float4*)(hl_tile + l * 128 + ks * 32 + quad * 8);
            float4 h0 = hp[0], h1 = hp[1];
            float v0 = fmaxf(h0.x + hr[ks][0], 0.f);
            float v1 = fmaxf(h0.y + hr[ks][1], 0.f);
            float v2 = fmaxf(h0.z + hr[ks][2], 0.f);
            float v3 = fmaxf(h0.w + hr[ks][3], 0.f);
            float v4 = fmaxf(h1.x + hr[ks][4], 0.f);
            float v5 = fmaxf(h1.y + hr[ks][5], 0.f);
            float v6 = fmaxf(h1.z + hr[ks][6], 0.f);
            float v7 = fmaxf(h1.w + hr[ks][7], 0.f);
            fp16x2 c0 = __builtin_amdgcn_cvt_pkrtz(v0, v1);
            fp16x2 c1 = __builtin_amdgcn_cvt_pkrtz(v2, v3);
            fp16x2 c2 = __builtin_amdgcn_cvt_pkrtz(v4, v5);
            fp16x2 c3 = __builtin_amdgcn_cvt_pkrtz(v6, v7);
            half8 t;
            t[0] = (_Float16)c0[0]; t[1] = (_Float16)c0[1];
            t[2] = (_Float16)c1[0]; t[3] = (_Float16)c1[1];
            t[4] = (_Float16)c2[0]; t[5] = (_Float16)c2[1];
            t[6] = (_Float16)c3[0]; t[7] = (_Float16)c3[1];
            a[ks] = t;
        }

        floatx4 acc[4];
#pragma unroll
        for (int nt = 0; nt < 4; ++nt)
            acc[nt] = (floatx4){0.f, 0.f, 0.f, 0.f};
#pragma unroll
        for (int ks = 0; ks < 4; ++ks)
#pragma unroll
            for (int nt = 0; nt < 4; ++nt)
                acc[nt] = __builtin_amdgcn_mfma_f32_16x16x32_f16(a[ks], w1f[ks][nt], acc[nt], 0, 0, 0);

        // h1 = relu(acc + b1); partial Dense(1) dot (lane covers n = nt*16+m)
        float p[4] = {0.f, 0.f, 0.f, 0.f};
#pragma unroll
        for (int nt = 0; nt < 4; ++nt)
#pragma unroll
            for (int r = 0; r < 4; ++r)
                p[r] += fmaxf(acc[nt][r] + b1v[nt], 0.f) * wrv[nt];

#pragma unroll
        for (int mask = 1; mask < 16; mask <<= 1)
#pragma unroll
            for (int r = 0; r < 4; ++r)
                p[r] += __shfl_xor(p[r], mask, 64);

        if (m < 4) {
            float v = p[m] + brv;                        // pair row = quad*4 + m
            float A = v > 0.f ? v : (expf(v) - 1.f);     // elu
            int r_out = rbase + wave * 16 + quad * 4 + m;
            int l_out = lbase + l;
            outA[l_out * 1024 + r_out] = A;
            if (br == 0)
                outB[l_out * 1024 + r_out] = (_Float16)A;   // Achg [ch][g]
            else
                outB[r_out * 1024 + l_out] = (_Float16)A;   // AgdT [d][g]
        }
    }
}

// ---------------------------------------------------------------- final GEMM + sigmoid
// C[ch][d] = sum_g Achg[ch][g]*Agd[g][d]; fp16 MFMA, fp32 accum.
__global__ __launch_bounds__(256) void gemm_sig(
    const _Float16* __restrict__ Ahf,   // [1024][1024] ch x g
    const _Float16* __restrict__ BThf,  // [1024][1024] d x g
    float* __restrict__ out0)
{
    __shared__ _Float16 At[64 * 72];   // +8 pad
    __shared__ _Float16 Bt[64 * 72];

    const int tid = threadIdx.x, lane = tid & 63, wave = tid >> 6;
    const int m = lane & 15, quad = lane >> 4;
    const int chbase = blockIdx.y * 64, dbase = blockIdx.x * 64;
    const int wrow = (wave >> 1) * 32, wcol = (wave & 1) * 32;

    floatx4 acc[2][2];
#pragma unroll
    for (int mi = 0; mi < 2; ++mi)
#pragma unroll
        for (int ni = 0; ni < 2; ++ni)
            acc[mi][ni] = (floatx4){0.f, 0.f, 0.f, 0.f};

    for (int kb = 0; kb < 1024; kb += 64) {
        __syncthreads();
#pragma unroll
        for (int i = 0; i < 2; ++i) {
            int idx = tid + i * 256;
            int row = idx >> 3, c4 = idx & 7;
            *(uint4*)(At + row * 72 + c4 * 8) =
                *(const uint4*)(Ahf + (chbase + row) * 1024 + kb + c4 * 8);
            *(uint4*)(Bt + row * 72 + c4 * 8) =
                *(const uint4*)(BThf + (dbase + row) * 1024 + kb + c4 * 8);
        }
        __syncthreads();
#pragma unroll
        for (int k2 = 0; k2 < 2; ++k2) {
            int koff = k2 * 32 + quad * 8;
            half8 a[2], b[2];
            a[0] = *(const half8*)(At + (wrow + m) * 72 + koff);
            a[1] = *(const half8*)(At + (wrow + 16 + m) * 72 + koff);
            b[0] = *(const half8*)(Bt + (wcol + m) * 72 + koff);
            b[1] = *(const half8*)(Bt + (wcol + 16 + m) * 72 + koff);
#pragma unroll
            for (int mi = 0; mi < 2; ++mi)
#pragma unroll
                for (int ni = 0; ni < 2; ++ni)
                    acc[mi][ni] = __builtin_amdgcn_mfma_f32_16x16x32_f16(a[mi], b[ni], acc[mi][ni], 0, 0, 0);
        }
    }

#pragma unroll
    for (int mi = 0; mi < 2; ++mi)
#pragma unroll
        for (int ni = 0; ni < 2; ++ni)
#pragma unroll
            for (int r = 0; r < 4; ++r) {
                int row = chbase + wrow + mi * 16 + quad * 4 + r;
                int col = dbase + wcol + ni * 16 + m;
                float v = acc[mi][ni][r];
                out0[row * 1024 + col] = 1.f / (1.f + expf(-v));
            }
}

// ---------------------------------------------------------------- launch
extern "C" void kernel_launch(void* const* d_in, const int* in_sizes, int n_in,
                              void* d_out, int out_size, void* d_ws, size_t ws_size,
                              hipStream_t stream) {
    const float* Xch = (const float*)d_in[0];
    const float* Xg  = (const float*)d_in[1];
    const float* Xd  = (const float*)d_in[2];
    const float* Wc0 = (const float*)d_in[3];
    const float* bc0 = (const float*)d_in[4];
    const float* Wc1 = (const float*)d_in[5];
    const float* bc1 = (const float*)d_in[6];
    const float* Wcr = (const float*)d_in[7];
    const float* bcr = (const float*)d_in[8];
    const float* Wd0 = (const float*)d_in[9];
    const float* bd0 = (const float*)d_in[10];
    const float* Wd1 = (const float*)d_in[11];
    const float* bd1 = (const float*)d_in[12];
    const float* Wdr = (const float*)d_in[13];
    const float* bdr = (const float*)d_in[14];

    float* out = (float*)d_out;
    float* wsf = (float*)d_ws;                           // 4x1024x128 fp32 = 2 MB
    _Float16* wsh = (_Float16*)(wsf + 524288);           // Achg f16 1M + AgdT f16 1M
    _Float16* w1frag = wsh + 2097152;                    // 16384 f16

    precompute_hlr<<<2048, 256, 0, stream>>>(Xch, Xg, Xd, Wc0, bc0, Wd0, bd0, wsf);
    pack_w1<<<64, 256, 0, stream>>>(Wc1, Wd1, w1frag);

    dim3 gb(16, 32, 2);   // (r-chunks of 64, l-chunks of 32, branch)
    branch_kernel<<<gb, 256, 0, stream>>>(wsf, bc1, Wcr, bcr, bd1, Wdr, bdr,
                                          w1frag, out, wsh);

    dim3 gg(16, 16);
    gemm_sig<<<gg, 16 * 16, 0, stream>>>(wsh, wsh + 1048576, out);
}